// Round 9
// baseline (166.669 us; speedup 1.0000x reference)
//
#include <hip/hip_runtime.h>
#include <stdint.h>

#define N_NODES 10000
#define N_EDGES 320000
#define DIM 256
#define NRANGE 4        // src ranges of 2500 nodes (~2.5MB of qv each, fits XCD L2)
#define RANGE_DIV 2500
#define PAD_SLOTS 32    // Poisson(8) per (node,range); P(>=32) ~ 5e-11, inputs fixed

typedef _Float16 half8 __attribute__((ext_vector_type(8)));
typedef _Float16 half2t __attribute__((ext_vector_type(2)));
typedef float floatx4 __attribute__((ext_vector_type(4)));

#define QK_SCALE 0.17677669529663687f  // 1/sqrt(32), folded into Wq/bq

// ---------------- async global->LDS (16B per lane, wave-uniform LDS base) ----------------
typedef __attribute__((address_space(3))) uint32_t lds_u32;
typedef __attribute__((address_space(1))) const uint32_t glob_u32;
__device__ __forceinline__ void load16_lds(const _Float16* g, _Float16* l) {
  __builtin_amdgcn_global_load_lds((glob_u32*)g, (lds_u32*)l, 16, 0, 0);
}

// ---------------- fp32 -> fp16 ----------------
__device__ __forceinline__ half8 cvt8s(const float4 a, const float4 b, float sc) {
  half8 o;
  o[0] = (_Float16)(a.x * sc); o[1] = (_Float16)(a.y * sc);
  o[2] = (_Float16)(a.z * sc); o[3] = (_Float16)(a.w * sc);
  o[4] = (_Float16)(b.x * sc); o[5] = (_Float16)(b.y * sc);
  o[6] = (_Float16)(b.z * sc); o[7] = (_Float16)(b.w * sc);
  return o;
}

// ---------------- prep: x cvt | weight cvt (+q scale) | cnt4 zero --------
// blocks [0,1250): x. [1250,1378): weights. [1378,1388): zero cnt4.
__global__ void __launch_bounds__(256) prep_k(
    const float* __restrict__ x, const float* __restrict__ Wq,
    const float* __restrict__ Wk, const float* __restrict__ Wv,
    const float* __restrict__ Wo,
    _Float16* __restrict__ xh, _Float16* __restrict__ Wcat,
    _Float16* __restrict__ Woh, int* __restrict__ cnt4) {
  int b = blockIdx.x;
  int t = threadIdx.x;
  if (b < 1250) {
    int i = b * 256 + t;  // 320000 = 1250*256 exactly
    const float4* p = (const float4*)x;
    ((half8*)xh)[i] = cvt8s(p[2 * i], p[2 * i + 1], 1.0f);
  } else if (b < 1378) {
    int bb = b - 1250;
    int w = bb >> 5;                 // 0..3
    int i = (bb & 31) * 256 + t;     // 0..8191
    const float* in = (w == 0) ? Wq : (w == 1) ? Wv : (w == 2) ? Wk : Wo;
    _Float16* out = (w < 3) ? (Wcat + (size_t)w * 65536) : Woh;
    float sc = (w == 0) ? QK_SCALE : 1.0f;
    const float4* p = (const float4*)in;
    ((half8*)out)[i] = cvt8s(p[2 * i], p[2 * i + 1], sc);
  } else {
    // zero cnt4: 10000 int4 across 10 blocks x 256 threads x 4 strided writes
    int idx = (b - 1378) * 256 + t;  // 0..2559
#pragma unroll
    for (int k = 0; k < 4; ++k) {
      int j = idx + k * 2560;
      if (j < 10000) ((int4*)cnt4)[j] = (int4){0, 0, 0, 0};
    }
  }
}

// ============ shared BK=32 double-buffered GEMM tile body (32KB LDS total) ============
// R17: R8 showed the BK=64/64KB-LDS GEMM at 46us, MfmaUtil 2.8%, occupancy 15% —
// latency-bound: 64KB LDS caps 2 blocks/CU, and each ks-barrier drains the full
// next-stage DMA (~600-900cy) with only 8 waves/CU to hide it. BK=32 (32KB LDS,
// structure verified in-run by R3's fused kernel) -> 5 blocks/CU, 2.5x TLP, and
// half the bytes per barrier-drain. 8 ks steps x 16 MFMA, same 128 MFMA total.
template <typename STORE>
__device__ __forceinline__ void gemm_tile32(
    _Float16* As, _Float16* Bs,  // [8192] halves each: 2 bufs x 8KB
    const _Float16* __restrict__ A, const _Float16* __restrict__ B,
    int m0, int n0, int t, STORE&& store_fn) {
  int lane = t & 63;
  int wid = t >> 6;
  int l16 = lane & 15;
  int quad = lane >> 4;
  int wm = wid >> 1, wn = wid & 1;

  floatx4 acc[4][4];
#pragma unroll
  for (int i = 0; i < 4; ++i)
#pragma unroll
    for (int j = 0; j < 4; ++j) acc[i][j] = (floatx4){0.f, 0.f, 0.f, 0.f};

  auto stage = [&](int ks, int buf) {
#pragma unroll
    for (int i = 0; i < 2; ++i) {
      int idx = i * 4 + wid;  // 0..7: chunk c = idx>>1, row-half hh2 = idx&1
      int c = idx >> 1;
      int hh2 = idx & 1;
      int r = hh2 * 64 + lane;
      int ar = m0 + r;
      if (ar >= N_NODES) ar = N_NODES - 1;
      load16_lds(A + (size_t)ar * 256 + ks * 32 + c * 8,
                 &As[buf * 4096 + (c * 128 + hh2 * 64) * 8]);
      load16_lds(B + (size_t)(n0 + r) * 256 + ks * 32 + c * 8,
                 &Bs[buf * 4096 + (c * 128 + hh2 * 64) * 8]);
    }
  };

  stage(0, 0);
  __syncthreads();  // drain DMA(0)

  for (int ks = 0; ks < 8; ++ks) {
    int bsel = ks & 1;
    if (ks < 7) stage(ks + 1, 1 - bsel);  // in flight during compute
    half8 af[4], bf[4];
#pragma unroll
    for (int i = 0; i < 4; ++i) {
      af[i] = *(const half8*)&As[bsel * 4096 + (quad * 128 + wm * 64 + i * 16 + l16) * 8];
      bf[i] = *(const half8*)&Bs[bsel * 4096 + (quad * 128 + wn * 64 + i * 16 + l16) * 8];
    }
#pragma unroll
    for (int mi = 0; mi < 4; ++mi)
#pragma unroll
      for (int ni = 0; ni < 4; ++ni)
        acc[mi][ni] =
            __builtin_amdgcn_mfma_f32_16x16x32_f16(af[mi], bf[ni], acc[mi][ni], 0, 0, 0);
    __syncthreads();  // drains DMA(ks+1) + protects buffer reuse
  }

#pragma unroll
  for (int mi = 0; mi < 4; ++mi) {
#pragma unroll
    for (int ni = 0; ni < 4; ++ni) {
      int col = n0 + wn * 64 + ni * 16 + l16;
#pragma unroll
      for (int r = 0; r < 4; ++r) {
        int row = m0 + wm * 64 + mi * 16 + quad * 4 + r;
        if (row < N_NODES) store_fn(row, col, acc[mi][ni][r]);
      }
    }
  }
}

// ---------------- merged QKV GEMM + edge scatter (independent block roles) -------------
// blocks [0,474): GEMM tiles. blocks [474,1024): scatter 582 edges each.
// With 32KB LDS all 1024 blocks are co-resident in one round (5 blocks/CU x 256).
__global__ void __launch_bounds__(256) gemm0_scatter_k(
    const _Float16* __restrict__ A, const _Float16* __restrict__ B,
    const float* __restrict__ b0, const float* __restrict__ b1,
    const float* __restrict__ b2,
    _Float16* __restrict__ qv, _Float16* __restrict__ kh,
    const int* __restrict__ src, const int* __restrict__ dst,
    int* __restrict__ cnt4, int* __restrict__ slist4) {
  __shared__ _Float16 As[8192];  // 2 bufs x 8KB
  __shared__ _Float16 Bs[8192];
  int u = blockIdx.x;
  int t = threadIdx.x;

  if (u >= 474) {
    // ---- scatter role ----
    int e0 = (u - 474) * 582;
    int e1 = e0 + 582;
    if (e1 > N_EDGES) e1 = N_EDGES;
    for (int e = e0 + t; e < e1; e += 256) {
      int s = src[e];
      int r = s / RANGE_DIV;  // 0..3
      int cell = dst[e] * NRANGE + r;
      int pos = atomicAdd(&cnt4[cell], 1);
      if (pos < PAD_SLOTS) slist4[cell * PAD_SLOTS + pos] = s;
    }
    return;
  }

  int bx = u % 79, by = u / 79;
  gemm_tile32(As, Bs, A, B, bx * 128, by * 128, t,
              [&](int row, int col, float v) {
                float bias = (col < 256) ? b0[col] * QK_SCALE
                                         : (col < 512) ? b1[col - 256] : b2[col - 512];
                float val = v + bias;
                if (col < 512)
                  qv[(size_t)row * 512 + col] = (_Float16)val;
                else
                  kh[(size_t)row * 256 + (col - 512)] = (_Float16)val;
              });
}

// ---------------- output-projection GEMM (fp32 out) ----------------
__global__ void __launch_bounds__(256) gemm1_k(
    const _Float16* __restrict__ A, const _Float16* __restrict__ B,
    const float* __restrict__ b0, float* __restrict__ outf) {
  __shared__ _Float16 As[8192];
  __shared__ _Float16 Bs[8192];
  int t = threadIdx.x;
  gemm_tile32(As, Bs, A, B, blockIdx.x * 128, blockIdx.y * 128, t,
              [&](int row, int col, float v) {
                outf[(size_t)row * 256 + col] = v + b0[col];
              });
}

// ---------------- fused score+softmax+aggregate (R7 best — unchanged) -------------
// One wave per node; 8 lanes/edge. h = lane&7 (head), g = lane>>3 (edge slot).
// Flattened range-major compact edge list; depth-1 q prefetch, v loaded early
// in-iteration. Head softmax = 3 shfl_xor; edge-slot reduce over bits 3..5.
__global__ void __launch_bounds__(256, 4) aggregate_k(
    const _Float16* __restrict__ qv, const _Float16* __restrict__ kh,
    const int* __restrict__ slist4, const int* __restrict__ cnt4,
    _Float16* __restrict__ hh) {
  int lane = threadIdx.x & 63;
  int n = blockIdx.x * 4 + (threadIdx.x >> 6);
  if (n >= N_NODES) return;
  int h = lane & 7;
  int g = lane >> 3;

  int4 cv = ((const int4*)cnt4)[n];
  int d0 = min(cv.x, PAD_SLOTS), d1 = min(cv.y, PAD_SLOTS);
  int d2 = min(cv.z, PAD_SLOTS), d3 = min(cv.w, PAD_SLOTS);
  int o1 = d0, o2 = o1 + d1, o3 = o2 + d2;
  int T = o3 + d3;
  const int* nb = slist4 + (size_t)n * (NRANGE * PAD_SLOTS);

  int sidA = 0, sidB = 0;
  {
    int i0 = lane;
    int r0 = (i0 >= o1) + (i0 >= o2) + (i0 >= o3);
    int b0r = (r0 == 0) ? 0 : (r0 == 1) ? o1 : (r0 == 2) ? o2 : o3;
    if (i0 < T) sidA = nb[r0 * PAD_SLOTS + (i0 - b0r)];
    if (T > 64) {
      int i1 = lane + 64;
      int r1 = (i1 >= o1) + (i1 >= o2) + (i1 >= o3);
      int b1r = (r1 == 0) ? 0 : (r1 == 1) ? o1 : (r1 == 2) ? o2 : o3;
      if (i1 < T) sidB = nb[r1 * PAD_SLOTS + (i1 - b1r)];
    }
  }

  half8 kc[4];
  const half8* krow = (const half8*)(kh + (size_t)n * DIM + h * 32);
#pragma unroll
  for (int i = 0; i < 4; ++i) kc[i] = krow[i];
  const half2t* k2 = (const half2t*)kc;

  half2t acc[16];
#pragma unroll
  for (int i = 0; i < 16; ++i) acc[i] = (half2t){(_Float16)0.f, (_Float16)0.f};

  int iters = (T + 7) >> 3;
  if (iters > 0) {
    int s0 = __shfl(sidA, g);
    const half8* rr = (const half8*)(qv + (size_t)s0 * 512 + h * 32);
    half8 qc[4];
#pragma unroll
    for (int i = 0; i < 4; ++i) qc[i] = rr[i];
    bool valid = g < T;

#pragma unroll 1
    for (int jj = 0; jj < iters; ++jj) {
      half8 vc[4];
#pragma unroll
      for (int i = 0; i < 4; ++i) vc[i] = rr[32 + i];
      half8 nq[4];
      bool nvalid = false;
      const half8* nrr = rr;
      if (jj + 1 < iters) {
        int nidx = (jj + 1) * 8 + g;
        int ns = (jj + 1 < 8) ? __shfl(sidA, nidx) : __shfl(sidB, nidx - 64);
        nrr = (const half8*)(qv + (size_t)ns * 512 + h * 32);
#pragma unroll
        for (int i = 0; i < 4; ++i) nq[i] = nrr[i];
        nvalid = nidx < T;
      }
      const half2t* q2 = (const half2t*)qc;
      float pa = 0.f, pb = 0.f, pc = 0.f, pd = 0.f;
#pragma unroll
      for (int i = 0; i < 4; ++i) {
#if __has_builtin(__builtin_amdgcn_fdot2)
        pa = __builtin_amdgcn_fdot2(q2[i], k2[i], pa, false);
        pb = __builtin_amdgcn_fdot2(q2[4 + i], k2[4 + i], pb, false);
        pc = __builtin_amdgcn_fdot2(q2[8 + i], k2[8 + i], pc, false);
        pd = __builtin_amdgcn_fdot2(q2[12 + i], k2[12 + i], pd, false);
#else
        pa += (float)q2[i][0] * (float)k2[i][0] + (float)q2[i][1] * (float)k2[i][1];
        pb += (float)q2[4 + i][0] * (float)k2[4 + i][0] + (float)q2[4 + i][1] * (float)k2[4 + i][1];
        pc += (float)q2[8 + i][0] * (float)k2[8 + i][0] + (float)q2[8 + i][1] * (float)k2[8 + i][1];
        pd += (float)q2[12 + i][0] * (float)k2[12 + i][0] + (float)q2[12 + i][1] * (float)k2[12 + i][1];
#endif
      }
      float p = (pa + pb) + (pc + pd);
      float ex = __expf(p);
      float ssum = ex;
      ssum += __shfl_xor(ssum, 1);
      ssum += __shfl_xor(ssum, 2);
      ssum += __shfl_xor(ssum, 4);
      float a = valid ? (ex * __frcp_rn(ssum)) : 0.f;
      _Float16 ah = (_Float16)a;
      half2t ah2 = (half2t){ah, ah};
      const half2t* v2 = (const half2t*)vc;
#pragma unroll
      for (int i = 0; i < 16; ++i) acc[i] += v2[i] * ah2;
#pragma unroll
      for (int i = 0; i < 4; ++i) qc[i] = nq[i];
      rr = nrr;
      valid = nvalid;
    }
  }

#pragma unroll
  for (int i = 0; i < 16; ++i) {
    union { half2t h2; int v; } u;
    u.h2 = acc[i]; u.v = __shfl_xor(u.v, 8);  acc[i] += u.h2;
    u.h2 = acc[i]; u.v = __shfl_xor(u.v, 16); acc[i] += u.h2;
    u.h2 = acc[i]; u.v = __shfl_xor(u.v, 32); acc[i] += u.h2;
  }
  if (g == 0) {
    half8* hrow = (half8*)(hh + (size_t)n * DIM + h * 32);
    const half8* a8 = (const half8*)acc;
#pragma unroll
    for (int i = 0; i < 4; ++i) hrow[i] = a8[i];
  }
}

// ---------------- launch: 4 dispatches, no memset ----------------
extern "C" void kernel_launch(void* const* d_in, const int* in_sizes, int n_in,
                              void* d_out, int out_size, void* d_ws, size_t ws_size,
                              hipStream_t stream) {
  const float* x = (const float*)d_in[0];
  const int* src = (const int*)d_in[1];
  const int* dst = (const int*)d_in[2];
  const float* Wq = (const float*)d_in[3];
  const float* bq = (const float*)d_in[4];
  const float* Wk = (const float*)d_in[5];
  const float* bk = (const float*)d_in[6];
  const float* Wv = (const float*)d_in[7];
  const float* bv = (const float*)d_in[8];
  const float* Wo = (const float*)d_in[9];
  const float* bo = (const float*)d_in[10];

  char* p = (char*)d_ws;
  const size_t SZ_NODE_H = (size_t)N_NODES * DIM * sizeof(_Float16);  // 5,120,000
  _Float16* xh = (_Float16*)p; p += SZ_NODE_H;
  _Float16* qvv = (_Float16*)p; p += 2 * SZ_NODE_H;  // [q|v] rows, 1KB each
  _Float16* kh = (_Float16*)p; p += SZ_NODE_H;
  _Float16* hh = (_Float16*)p; p += SZ_NODE_H;
  _Float16* Wcat = (_Float16*)p; p += (size_t)768 * 256 * sizeof(_Float16);
  _Float16* Woh = (_Float16*)p; p += (size_t)256 * 256 * sizeof(_Float16);
  int* cnt4 = (int*)p; p += (size_t)N_NODES * NRANGE * sizeof(int);  // 160KB
  int* slist4 = (int*)p; p += (size_t)N_NODES * NRANGE * PAD_SLOTS * sizeof(int);  // 5.12MB

  // 1) cvt x + weights + zero cnt4
  prep_k<<<1388, 256, 0, stream>>>(x, Wq, Wk, Wv, Wo, xh, Wcat, Woh, cnt4);

  // 2) fused QKV projection (474 tiles) || edge scatter (550 blocks)
  gemm0_scatter_k<<<1024, 256, 0, stream>>>(xh, Wcat, bq, bv, bk, qvv, kh,
                                            src, dst, cnt4, slist4);

  // 3) flattened-range aggregate
  aggregate_k<<<2500, 256, 0, stream>>>(qvv, kh, slist4, cnt4, hh);

  // 4) output projection -> fp32
  gemm1_k<<<dim3(79, 2), 256, 0, stream>>>(hh, Woh, bo, (float*)d_out);
}